// Round 1
// baseline (410.844 us; speedup 1.0000x reference)
//
#include <hip/hip_runtime.h>

// Problem constants (MultiScaleRetention: B=4, L=4096, D=1024, H=16, DH=64)
#define BB 4
#define LL 4096
#define DM 1024
#define NH 16
#define DHD 64
#define MM (BB * LL)   // 16384 rows
#define CC 64          // scan chunks per sequence
#define LC 64          // chunk length (CC*LC == LL)

typedef unsigned short u16;
typedef unsigned short u16x8 __attribute__((ext_vector_type(8)));
typedef float f32x4 __attribute__((ext_vector_type(4)));
// gfx950 mfma_f32_16x16x32_bf16 takes V8 __bf16 per LLVM BuiltinsAMDGPU.def.
typedef __bf16 mfma_in __attribute__((ext_vector_type(8)));

__device__ __forceinline__ u16 f2bf(float f) {
    unsigned u = __float_as_uint(f);
    u += 0x7FFFu + ((u >> 16) & 1u);   // RNE
    return (u16)(u >> 16);
}
__device__ __forceinline__ float bf2f(u16 u) {
    return __uint_as_float(((unsigned)u) << 16);
}

// ---------------------------------------------------------------- conversions
__global__ void cvt_f32_bf16(const float* __restrict__ src, u16* __restrict__ dst, int n4) {
    int i = blockIdx.x * blockDim.x + threadIdx.x;
    if (i < n4) {
        float4 f = ((const float4*)src)[i];
        ushort4 o;
        o.x = f2bf(f.x); o.y = f2bf(f.y); o.z = f2bf(f.z); o.w = f2bf(f.w);
        ((ushort4*)dst)[i] = o;
    }
}

// ---------------------------------------------------------------- GEMM: C = A @ B^T
// A: MxK bf16 row-major, B: NxK bf16 row-major, C: MxN (bf16 or f32)
// 128x128 block tile, BK=32, 256 threads = 4 waves, each wave 4x4 tiles of 16x16x32.
template <int OUTF>
__global__ __launch_bounds__(256)
void gemm_nt(const u16* __restrict__ A, const u16* __restrict__ B,
             void* __restrict__ Cv, int M, int N, int K) {
    __shared__ u16x8 As[512];  // 128 rows x 32 k  (row*4 + k/8)
    __shared__ u16x8 Bs[512];

    const int tid  = threadIdx.x;
    const int wave = tid >> 6;
    const int lane = tid & 63;
    const int quad = lane >> 4;
    const int l16  = lane & 15;
    const int mBlk = blockIdx.x * 128;
    const int nBlk = blockIdx.y * 128;
    const int wm   = (wave >> 1) * 64;
    const int wn   = (wave & 1) * 64;

    const int r0 = tid >> 2;        // staging row 0..63
    const int q0 = tid & 3;         // staging k-chunk

    f32x4 acc[4][4] = {};

    const u16* Abase = A + (size_t)(mBlk + r0) * K + q0 * 8;
    const u16* Bbase = B + (size_t)(nBlk + r0) * K + q0 * 8;

    for (int kt = 0; kt < K; kt += 32) {
        u16x8 a0 = *(const u16x8*)(Abase + kt);
        u16x8 a1 = *(const u16x8*)(Abase + kt + (size_t)64 * K);
        u16x8 b0 = *(const u16x8*)(Bbase + kt);
        u16x8 b1 = *(const u16x8*)(Bbase + kt + (size_t)64 * K);
        __syncthreads();   // protect previous iteration's LDS reads
        As[r0 * 4 + q0]        = a0;
        As[(r0 + 64) * 4 + q0] = a1;
        Bs[r0 * 4 + q0]        = b0;
        Bs[(r0 + 64) * 4 + q0] = b1;
        __syncthreads();

        mfma_in af[4], bfr[4];
#pragma unroll
        for (int i = 0; i < 4; i++)
            af[i] = __builtin_bit_cast(mfma_in, As[(wm + i * 16 + l16) * 4 + quad]);
#pragma unroll
        for (int j = 0; j < 4; j++)
            bfr[j] = __builtin_bit_cast(mfma_in, Bs[(wn + j * 16 + l16) * 4 + quad]);
#pragma unroll
        for (int i = 0; i < 4; i++)
#pragma unroll
            for (int j = 0; j < 4; j++)
                acc[i][j] = __builtin_amdgcn_mfma_f32_16x16x32_bf16(af[i], bfr[j], acc[i][j], 0, 0, 0);
    }

    // epilogue: D row = quad*4 + reg, col = lane&15 (m89/m91-verified layout)
#pragma unroll
    for (int i = 0; i < 4; i++) {
        int row0 = mBlk + wm + i * 16 + quad * 4;
#pragma unroll
        for (int j = 0; j < 4; j++) {
            int col = nBlk + wn + j * 16 + l16;
#pragma unroll
            for (int r = 0; r < 4; r++) {
                float val = acc[i][j][r];
                if (OUTF) ((float*)Cv)[(size_t)(row0 + r) * N + col] = val;
                else      ((u16*)Cv)[(size_t)(row0 + r) * N + col]  = f2bf(val);
            }
        }
    }
}

// ---------------------------------------------------------------- scan phase A:
// local (seed=0) scan per chunk, store chunk-end value.
// grid: (DM/256, CC, BB), 256 threads
__global__ __launch_bounds__(256)
void scan_ends(const u16* __restrict__ v, const float* __restrict__ beta,
               float* __restrict__ ebuf) {
    int d = blockIdx.x * 256 + threadIdx.x;
    int c = blockIdx.y, b = blockIdx.z;
    int h = d >> 6;
    float lam = 1.0f / (1.0f + __expf(-beta[h]));
    size_t idx = ((size_t)b * LL + (size_t)c * LC) * DM + d;
    float s = 0.0f;
#pragma unroll 4
    for (int i = 0; i < LC; i++) {
        s = lam * s + bf2f(v[idx]);
        idx += DM;
    }
    ebuf[((size_t)b * CC + c) * DM + d] = s;
}

// ---------------------------------------------------------------- scan phase B:
// sequential combine of CC chunk-ends per channel -> carry-in per chunk.
// grid: BB*DM/256 blocks
__global__ __launch_bounds__(256)
void scan_carry(const float* __restrict__ ebuf, const float* __restrict__ beta,
                float* __restrict__ carry) {
    int ch = blockIdx.x * 256 + threadIdx.x;  // 0..BB*DM-1
    int b = ch >> 10, d = ch & 1023;
    int h = d >> 6;
    float lam = 1.0f / (1.0f + __expf(-beta[h]));
    float lamLc = lam;
    for (int i = 0; i < 6; i++) lamLc *= lamLc;  // lam^64 exactly
    float cur = 0.0f;
    for (int c = 0; c < CC; c++) {
        size_t idx = ((size_t)b * CC + c) * DM + d;
        carry[idx] = cur;                 // state entering chunk c
        cur = lamLc * cur + ebuf[idx];
    }
}

// ---------------------------------------------------------------- scan phase C:
// seeded re-scan, fused y = q * state (bf16 out).
// grid: (DM/256, CC, BB)
__global__ __launch_bounds__(256)
void scan_apply(const u16* __restrict__ v, const u16* __restrict__ q,
                const float* __restrict__ carry, const float* __restrict__ beta,
                u16* __restrict__ y) {
    int d = blockIdx.x * 256 + threadIdx.x;
    int c = blockIdx.y, b = blockIdx.z;
    int h = d >> 6;
    float lam = 1.0f / (1.0f + __expf(-beta[h]));
    float s = carry[((size_t)b * CC + c) * DM + d];
    size_t idx = ((size_t)b * LL + (size_t)c * LC) * DM + d;
#pragma unroll 4
    for (int i = 0; i < LC; i++) {
        s = lam * s + bf2f(v[idx]);
        y[idx] = f2bf(bf2f(q[idx]) * s);
        idx += DM;
    }
}

// ---------------------------------------------------------------- LayerNorm + SiLU gate
// one block per row (B*L rows), 256 threads x 4 elements
__global__ __launch_bounds__(256)
void ln_gate(const u16* __restrict__ y, const u16* __restrict__ g,
             const float* __restrict__ gamma, const float* __restrict__ lnb,
             u16* __restrict__ out) {
    __shared__ float red[8];
    int row = blockIdx.x;
    int tid = threadIdx.x;
    int wave = tid >> 6, lane = tid & 63;
    size_t base = (size_t)row * DM;

    float vals[4];
    float sum = 0.0f, sq = 0.0f;
#pragma unroll
    for (int j = 0; j < 4; j++) {
        float x = bf2f(y[base + tid + j * 256]);
        vals[j] = x;
        sum += x;
        sq += x * x;
    }
#pragma unroll
    for (int off = 32; off > 0; off >>= 1) {
        sum += __shfl_down(sum, off);
        sq  += __shfl_down(sq, off);
    }
    if (lane == 0) { red[wave] = sum; red[4 + wave] = sq; }
    __syncthreads();
    if (tid == 0) {
        red[0] = red[0] + red[1] + red[2] + red[3];
        red[4] = red[4] + red[5] + red[6] + red[7];
    }
    __syncthreads();
    float mu  = red[0] * (1.0f / DM);
    float var = red[4] * (1.0f / DM) - mu * mu;
    float inv = rsqrtf(var + 1e-5f);
#pragma unroll
    for (int j = 0; j < 4; j++) {
        int d = tid + j * 256;
        float x  = (vals[j] - mu) * inv * gamma[d] + lnb[d];
        float gg = bf2f(g[base + d]);
        float gate = gg / (1.0f + __expf(-gg));
        out[base + d] = f2bf(x * gate);
    }
}

// ---------------------------------------------------------------- launcher
extern "C" void kernel_launch(void* const* d_in, const int* in_sizes, int n_in,
                              void* d_out, int out_size, void* d_ws, size_t ws_size,
                              hipStream_t stream) {
    const float* x     = (const float*)d_in[0];
    const float* Wq    = (const float*)d_in[1];
    const float* Wv    = (const float*)d_in[2];
    const float* Wg    = (const float*)d_in[3];
    const float* Wo    = (const float*)d_in[4];
    const float* beta  = (const float*)d_in[5];
    const float* gamma = (const float*)d_in[6];
    const float* lnb   = (const float*)d_in[7];

    // workspace layout (bf16 elements)
    u16* xb  = (u16*)d_ws;                    // 16384x1024, reused as y_pre
    u16* Wqb = xb + (size_t)MM * DM;
    u16* Wvb = Wqb + (size_t)DM * DM;
    u16* Wgb = Wvb + (size_t)DM * DM;
    u16* Wob = Wgb + (size_t)DM * DM;
    u16* qb  = Wob + (size_t)DM * DM;
    u16* vb  = qb + (size_t)MM * DM;          // reused as y_final
    u16* gb  = vb + (size_t)MM * DM;
    float* ebuf  = (float*)(gb + (size_t)MM * DM);   // B*CC*DM
    float* carry = ebuf + (size_t)BB * CC * DM;
    u16* ypre = xb;
    u16* yfin = vb;

    // 1) fp32 -> bf16 conversions
    {
        int n4 = MM * DM / 4;
        cvt_f32_bf16<<<(n4 + 255) / 256, 256, 0, stream>>>(x, xb, n4);
        int w4 = DM * DM / 4;
        cvt_f32_bf16<<<(w4 + 255) / 256, 256, 0, stream>>>(Wq, Wqb, w4);
        cvt_f32_bf16<<<(w4 + 255) / 256, 256, 0, stream>>>(Wv, Wvb, w4);
        cvt_f32_bf16<<<(w4 + 255) / 256, 256, 0, stream>>>(Wg, Wgb, w4);
        cvt_f32_bf16<<<(w4 + 255) / 256, 256, 0, stream>>>(Wo, Wob, w4);
    }

    // 2) projections q, v, g
    dim3 gg(MM / 128, DM / 128);
    gemm_nt<0><<<gg, 256, 0, stream>>>(xb, Wqb, qb, MM, DM, DM);
    gemm_nt<0><<<gg, 256, 0, stream>>>(xb, Wvb, vb, MM, DM, DM);
    gemm_nt<0><<<gg, 256, 0, stream>>>(xb, Wgb, gb, MM, DM, DM);

    // 3) retention scan (chunked)
    dim3 gs(DM / 256, CC, BB);
    scan_ends<<<gs, 256, 0, stream>>>(vb, beta, ebuf);
    scan_carry<<<(BB * DM) / 256, 256, 0, stream>>>(ebuf, beta, carry);
    scan_apply<<<gs, 256, 0, stream>>>(vb, qb, carry, beta, ypre);

    // 4) LayerNorm + SiLU gate
    ln_gate<<<MM, 256, 0, stream>>>(ypre, gb, gamma, lnb, yfin);

    // 5) output projection (fp32 out)
    gemm_nt<1><<<gg, 256, 0, stream>>>(yfin, Wob, d_out, MM, DM, DM);
}

// Round 2
// 400.072 us; speedup vs baseline: 1.0269x; 1.0269x over previous
//
#include <hip/hip_runtime.h>

// Problem constants (MultiScaleRetention: B=4, L=4096, D=1024, H=16, DH=64)
#define BB 4
#define LL 4096
#define DM 1024
#define NH 16
#define MM (BB * LL)   // 16384 rows
#define CC2 256        // scan chunks per sequence (phase-C fused granularity)
#define LC2 16         // chunk length (CC2*LC2 == LL)

typedef unsigned short u16;
typedef unsigned short u16x8 __attribute__((ext_vector_type(8)));
typedef float f32x4 __attribute__((ext_vector_type(4)));
typedef __bf16 mfma_in __attribute__((ext_vector_type(8)));

__device__ __forceinline__ u16 f2bf(float f) {
    unsigned u = __float_as_uint(f);
    u += 0x7FFFu + ((u >> 16) & 1u);   // RNE
    return (u16)(u >> 16);
}
__device__ __forceinline__ float bf2f(u16 u) {
    return __uint_as_float(((unsigned)u) << 16);
}

// async global->LDS, 16B per lane; LDS dest = wave-uniform base + lane*16
__device__ __forceinline__ void gld_lds16(const u16* g, u16* l) {
    __builtin_amdgcn_global_load_lds(
        (const __attribute__((address_space(1))) void*)g,
        (__attribute__((address_space(3))) void*)l,
        16, 0, 0);
}

// ---------------------------------------------------------------- conversions
__global__ void cvt_f32_bf16(const float* __restrict__ src, u16* __restrict__ dst, int n4) {
    int i = blockIdx.x * blockDim.x + threadIdx.x;
    if (i < n4) {
        float4 f = ((const float4*)src)[i];
        ushort4 o;
        o.x = f2bf(f.x); o.y = f2bf(f.y); o.z = f2bf(f.z); o.w = f2bf(f.w);
        ((ushort4*)dst)[i] = o;
    }
}

// all 4 weight matrices in one launch; blockIdx.y selects the matrix
__global__ void cvt_weights(const float* __restrict__ w0, const float* __restrict__ w1,
                            const float* __restrict__ w2, const float* __restrict__ w3,
                            u16* __restrict__ dst, int n4) {
    const float* srcs[4] = {w0, w1, w2, w3};
    const float* src = srcs[blockIdx.y];
    u16* d = dst + (size_t)blockIdx.y * DM * DM;
    int i = blockIdx.x * blockDim.x + threadIdx.x;
    if (i < n4) {
        float4 f = ((const float4*)src)[i];
        ushort4 o;
        o.x = f2bf(f.x); o.y = f2bf(f.y); o.z = f2bf(f.z); o.w = f2bf(f.w);
        ((ushort4*)d)[i] = o;
    }
}

// ---------------------------------------------------------------- GEMM: C = A @ B^T
// A: MxK bf16 rm, B: NxK bf16 rm, C: MxN (bf16 or f32)
// 128x128 tile, BK=32, 4 waves x (4x4) 16x16x32 MFMA, async LDS staging (m97 structure)
template <int OUTF>
__global__ __launch_bounds__(256)
void gemm_nt(const u16* __restrict__ A, const u16* __restrict__ B,
             void* __restrict__ Cv, int M, int N, int K) {
    __shared__ u16 As[128 * 32];  // row*32 + k
    __shared__ u16 Bs[128 * 32];

    const int tid  = threadIdx.x;
    const int wave = tid >> 6;
    const int lane = tid & 63;
    const int quad = lane >> 4;
    const int l16  = lane & 15;
    const int mBlk = blockIdx.x * 128;
    const int nBlk = blockIdx.y * 128;
    const int wm   = (wave >> 1) * 64;
    const int wn   = (wave & 1) * 64;

    // staging: wave w lane l -> row w*16 + l/4 (+64), k-chunk (l&3)*8
    const int srow   = wave * 16 + (lane >> 2);
    const int schunk = (lane & 3) * 8;

    const u16* gA0 = A + (size_t)(mBlk + srow) * K + schunk;
    const u16* gA1 = gA0 + (size_t)64 * K;
    const u16* gB0 = B + (size_t)(nBlk + srow) * K + schunk;
    const u16* gB1 = gB0 + (size_t)64 * K;

    u16* lA0 = As + wave * 16 * 32;  // wave-uniform LDS base
    u16* lA1 = lA0 + 64 * 32;
    u16* lB0 = Bs + wave * 16 * 32;
    u16* lB1 = lB0 + 64 * 32;

    f32x4 acc[4][4] = {};

    for (int kt = 0; kt < K; kt += 32) {
        __syncthreads();   // protect previous iteration's LDS reads
        gld_lds16(gA0 + kt, lA0);
        gld_lds16(gA1 + kt, lA1);
        gld_lds16(gB0 + kt, lB0);
        gld_lds16(gB1 + kt, lB1);
        __syncthreads();   // drains vmcnt -> staged data visible

        mfma_in af[4], bfr[4];
#pragma unroll
        for (int i = 0; i < 4; i++)
            af[i] = *(const mfma_in*)&As[(wm + i * 16 + l16) * 32 + quad * 8];
#pragma unroll
        for (int j = 0; j < 4; j++)
            bfr[j] = *(const mfma_in*)&Bs[(wn + j * 16 + l16) * 32 + quad * 8];
#pragma unroll
        for (int i = 0; i < 4; i++)
#pragma unroll
            for (int j = 0; j < 4; j++)
                acc[i][j] = __builtin_amdgcn_mfma_f32_16x16x32_bf16(af[i], bfr[j], acc[i][j], 0, 0, 0);
    }

    // epilogue: D row = quad*4 + reg, col = lane&15 (m89/m91-verified layout)
#pragma unroll
    for (int i = 0; i < 4; i++) {
        int row0 = mBlk + wm + i * 16 + quad * 4;
#pragma unroll
        for (int j = 0; j < 4; j++) {
            int col = nBlk + wn + j * 16 + l16;
#pragma unroll
            for (int r = 0; r < 4; r++) {
                float val = acc[i][j][r];
                if (OUTF) ((float*)Cv)[(size_t)(row0 + r) * N + col] = val;
                else      ((u16*)Cv)[(size_t)(row0 + r) * N + col]  = f2bf(val);
            }
        }
    }
}

// ---------------------------------------------------------------- scan phase A:
// local (seed=0) scan per chunk of 16, store chunk-end value.
// grid: (DM/256, CC2, BB)
__global__ __launch_bounds__(256)
void scan_ends(const u16* __restrict__ v, const float* __restrict__ beta,
               float* __restrict__ ebuf) {
    int d = blockIdx.x * 256 + threadIdx.x;
    int c = blockIdx.y, b = blockIdx.z;
    int h = d >> 6;
    float lam = 1.0f / (1.0f + __expf(-beta[h]));
    size_t idx = ((size_t)b * LL + (size_t)c * LC2) * DM + d;
    float s = 0.0f;
#pragma unroll
    for (int i = 0; i < LC2; i++) {
        s = lam * s + bf2f(v[idx]);
        idx += DM;
    }
    ebuf[((size_t)b * CC2 + c) * DM + d] = s;
}

// ---------------------------------------------------------------- scan phase B:
// sequential combine of CC2 chunk-ends per channel -> carry-in per chunk.
// loads are address-independent of the serial chain -> prefetchable.
__global__ __launch_bounds__(256)
void scan_carry(const float* __restrict__ ebuf, const float* __restrict__ beta,
                float* __restrict__ carry) {
    int ch = blockIdx.x * 256 + threadIdx.x;  // 0..BB*DM-1
    int b = ch >> 10, d = ch & 1023;
    int h = d >> 6;
    float lam = 1.0f / (1.0f + __expf(-beta[h]));
    float lamC = lam;
    for (int i = 0; i < 4; i++) lamC *= lamC;  // lam^16
    float cur = 0.0f;
#pragma unroll 8
    for (int c = 0; c < CC2; c++) {
        size_t idx = ((size_t)b * CC2 + c) * DM + d;
        carry[idx] = cur;                 // state entering chunk c
        cur = lamC * cur + ebuf[idx];
    }
}

// ---------------------------------------------------------------- scan phase C,
// fused: seeded re-scan + y=q*state + LayerNorm + SiLU gate -> bf16 out.
// block = full row (1024 ch, thread owns 4) x LC2 rows; grid (CC2, BB).
__global__ __launch_bounds__(256)
void scan_ln_gate(const u16* __restrict__ v, const u16* __restrict__ q,
                  const u16* __restrict__ g, const float* __restrict__ carry,
                  const float* __restrict__ beta, const float* __restrict__ gamma,
                  const float* __restrict__ lnb, u16* __restrict__ out) {
    __shared__ float red[2][8];
    const int t = threadIdx.x;
    const int c = blockIdx.x, b = blockIdx.y;
    const int wave = t >> 6, lane = t & 63;
    const int d0 = t * 4;
    const int h = d0 >> 6;
    float lam = 1.0f / (1.0f + __expf(-beta[h]));
    float4 gm = ((const float4*)gamma)[t];
    float4 bt = ((const float4*)lnb)[t];
    float4 cr = *(const float4*)(carry + ((size_t)b * CC2 + c) * DM + d0);
    float s0 = cr.x, s1 = cr.y, s2 = cr.z, s3 = cr.w;
    size_t base = ((size_t)b * LL + (size_t)c * LC2) * DM + d0;

    for (int i = 0; i < LC2; i++) {
        ushort4 v4 = *(const ushort4*)(v + base);
        ushort4 q4 = *(const ushort4*)(q + base);
        ushort4 g4 = *(const ushort4*)(g + base);
        s0 = lam * s0 + bf2f(v4.x);
        s1 = lam * s1 + bf2f(v4.y);
        s2 = lam * s2 + bf2f(v4.z);
        s3 = lam * s3 + bf2f(v4.w);
        float y0 = bf2f(q4.x) * s0, y1 = bf2f(q4.y) * s1;
        float y2 = bf2f(q4.z) * s2, y3 = bf2f(q4.w) * s3;
        float sum = y0 + y1 + y2 + y3;
        float sq  = y0 * y0 + y1 * y1 + y2 * y2 + y3 * y3;
#pragma unroll
        for (int off = 32; off > 0; off >>= 1) {
            sum += __shfl_xor(sum, off);
            sq  += __shfl_xor(sq, off);
        }
        int p = i & 1;
        if (lane == 0) { red[p][wave] = sum; red[p][4 + wave] = sq; }
        __syncthreads();
        float ts = red[p][0] + red[p][1] + red[p][2] + red[p][3];
        float tq = red[p][4] + red[p][5] + red[p][6] + red[p][7];
        float mu  = ts * (1.0f / DM);
        float inv = rsqrtf(tq * (1.0f / DM) - mu * mu + 1e-5f);

        float gv0 = bf2f(g4.x), gv1 = bf2f(g4.y), gv2 = bf2f(g4.z), gv3 = bf2f(g4.w);
        float x0 = ((y0 - mu) * inv * gm.x + bt.x) * (gv0 / (1.0f + __expf(-gv0)));
        float x1 = ((y1 - mu) * inv * gm.y + bt.y) * (gv1 / (1.0f + __expf(-gv1)));
        float x2 = ((y2 - mu) * inv * gm.z + bt.z) * (gv2 / (1.0f + __expf(-gv2)));
        float x3 = ((y3 - mu) * inv * gm.w + bt.w) * (gv3 / (1.0f + __expf(-gv3)));
        ushort4 o;
        o.x = f2bf(x0); o.y = f2bf(x1); o.z = f2bf(x2); o.w = f2bf(x3);
        *(ushort4*)(out + base) = o;
        base += DM;
    }
}

// ---------------------------------------------------------------- launcher
extern "C" void kernel_launch(void* const* d_in, const int* in_sizes, int n_in,
                              void* d_out, int out_size, void* d_ws, size_t ws_size,
                              hipStream_t stream) {
    const float* x     = (const float*)d_in[0];
    const float* Wq    = (const float*)d_in[1];
    const float* Wv    = (const float*)d_in[2];
    const float* Wg    = (const float*)d_in[3];
    const float* Wo    = (const float*)d_in[4];
    const float* beta  = (const float*)d_in[5];
    const float* gamma = (const float*)d_in[6];
    const float* lnb   = (const float*)d_in[7];

    // workspace layout (bf16 elements)
    u16* xb  = (u16*)d_ws;                    // 16384x1024; reused as y_final after 3rd GEMM
    u16* Wqb = xb + (size_t)MM * DM;
    u16* Wvb = Wqb + (size_t)DM * DM;
    u16* Wgb = Wvb + (size_t)DM * DM;
    u16* Wob = Wgb + (size_t)DM * DM;
    u16* qb  = Wob + (size_t)DM * DM;
    u16* vb  = qb + (size_t)MM * DM;
    u16* gb  = vb + (size_t)MM * DM;
    float* ebuf  = (float*)(gb + (size_t)MM * DM);   // B*CC2*DM f32
    float* carry = ebuf + (size_t)BB * CC2 * DM;
    u16* yfin = xb;

    // 1) fp32 -> bf16 conversions
    {
        int n4 = MM * DM / 4;
        cvt_f32_bf16<<<(n4 + 255) / 256, 256, 0, stream>>>(x, xb, n4);
        int w4 = DM * DM / 4;
        dim3 gw((w4 + 255) / 256, 4);
        cvt_weights<<<gw, 256, 0, stream>>>(Wq, Wv, Wg, Wo, Wqb, w4);
    }

    // 2) projections q, v, g
    dim3 gg(MM / 128, DM / 128);
    gemm_nt<0><<<gg, 256, 0, stream>>>(xb, Wqb, qb, MM, DM, DM);
    gemm_nt<0><<<gg, 256, 0, stream>>>(xb, Wvb, vb, MM, DM, DM);
    gemm_nt<0><<<gg, 256, 0, stream>>>(xb, Wgb, gb, MM, DM, DM);

    // 3) retention scan (chunked, LC2=16) + fused LN + SiLU gate
    dim3 gs(DM / 256, CC2, BB);
    scan_ends<<<gs, 256, 0, stream>>>(vb, beta, ebuf);
    scan_carry<<<(BB * DM) / 256, 256, 0, stream>>>(ebuf, beta, carry);
    dim3 gf(CC2, BB);
    scan_ln_gate<<<gf, 256, 0, stream>>>(vb, qb, gb, carry, beta, gamma, lnb, yfin);

    // 4) output projection (fp32 out)
    gemm_nt<1><<<gg, 256, 0, stream>>>(yfin, Wob, d_out, MM, DM, DM);
}

// Round 3
// 378.229 us; speedup vs baseline: 1.0862x; 1.0577x over previous
//
#include <hip/hip_runtime.h>

// Problem constants (MultiScaleRetention: B=4, L=4096, D=1024, H=16, DH=64)
#define BB 4
#define LL 4096
#define DM 1024
#define NH 16
#define MM (BB * LL)   // 16384 rows
#define CC2 256        // scan chunks per sequence
#define LC2 16         // chunk length (CC2*LC2 == LL)

typedef unsigned short u16;
typedef float f32x4 __attribute__((ext_vector_type(4)));
typedef __bf16 mfma_in __attribute__((ext_vector_type(8)));

__device__ __forceinline__ u16 f2bf(float f) {
    unsigned u = __float_as_uint(f);
    u += 0x7FFFu + ((u >> 16) & 1u);   // RNE
    return (u16)(u >> 16);
}
__device__ __forceinline__ float bf2f(u16 u) {
    return __uint_as_float(((unsigned)u) << 16);
}

// async global->LDS, 16B per lane; LDS dest = wave-uniform base + lane*16
__device__ __forceinline__ void gld_lds16(const u16* g, u16* l) {
    __builtin_amdgcn_global_load_lds(
        (const __attribute__((address_space(1))) void*)g,
        (__attribute__((address_space(3))) void*)l,
        16, 0, 0);
}

// ---------------------------------------------------------------- conversions
// one launch converts x (MM*DM) and the 4 weight matrices (4*DM*DM) -> contiguous dst
#define XF4 (MM * DM / 4)            // 4,194,304 float4s of x
#define WF4 (DM * DM / 4)            // 262,144 float4s per weight
__global__ __launch_bounds__(256)
void cvt_all(const float* __restrict__ x,
             const float* __restrict__ w0, const float* __restrict__ w1,
             const float* __restrict__ w2, const float* __restrict__ w3,
             u16* __restrict__ dst) {
    int i = blockIdx.x * 256 + threadIdx.x;
    const float* src;
    int si;
    if (i < XF4) { src = x; si = i; }
    else {
        int j = i - XF4;
        const float* ws[4] = {w0, w1, w2, w3};
        src = ws[j >> 18];
        si = j & (WF4 - 1);
    }
    float4 f = ((const float4*)src)[si];
    ushort4 o;
    o.x = f2bf(f.x); o.y = f2bf(f.y); o.z = f2bf(f.z); o.w = f2bf(f.w);
    ((ushort4*)dst)[i] = o;
}

// ---------------------------------------------------------------- GEMM core macro body
// A: MxK bf16 rm, B: NxK bf16 rm. 128x128 tile, BK=32, 4 waves x (4x4) 16x16x32 MFMA,
// async LDS staging (m97 structure). acc left in acc[4][4]; row/col computed by caller.

// fused q/v/g projection: B is the concatenated 3072x1024 weight; 3 bf16 outputs
__global__ __launch_bounds__(256)
void gemm_qvg(const u16* __restrict__ A, const u16* __restrict__ B,
              u16* __restrict__ oq, u16* __restrict__ ov, u16* __restrict__ og,
              int K) {
    __shared__ u16 As[128 * 32];
    __shared__ u16 Bs[128 * 32];

    const int tid  = threadIdx.x;
    const int wave = tid >> 6;
    const int lane = tid & 63;
    const int quad = lane >> 4;
    const int l16  = lane & 15;
    const int mBlk = blockIdx.x * 128;
    const int nBlk = blockIdx.y * 128;   // 0..2944 within concatenated 3072
    const int wm   = (wave >> 1) * 64;
    const int wn   = (wave & 1) * 64;

    const int srow   = wave * 16 + (lane >> 2);
    const int schunk = (lane & 3) * 8;

    const u16* gA0 = A + (size_t)(mBlk + srow) * K + schunk;
    const u16* gA1 = gA0 + (size_t)64 * K;
    const u16* gB0 = B + (size_t)(nBlk + srow) * K + schunk;
    const u16* gB1 = gB0 + (size_t)64 * K;

    u16* lA0 = As + wave * 16 * 32;
    u16* lA1 = lA0 + 64 * 32;
    u16* lB0 = Bs + wave * 16 * 32;
    u16* lB1 = lB0 + 64 * 32;

    f32x4 acc[4][4] = {};

    for (int kt = 0; kt < K; kt += 32) {
        __syncthreads();
        gld_lds16(gA0 + kt, lA0);
        gld_lds16(gA1 + kt, lA1);
        gld_lds16(gB0 + kt, lB0);
        gld_lds16(gB1 + kt, lB1);
        __syncthreads();

        mfma_in af[4], bfr[4];
#pragma unroll
        for (int i = 0; i < 4; i++)
            af[i] = *(const mfma_in*)&As[(wm + i * 16 + l16) * 32 + quad * 8];
#pragma unroll
        for (int j = 0; j < 4; j++)
            bfr[j] = *(const mfma_in*)&Bs[(wn + j * 16 + l16) * 32 + quad * 8];
#pragma unroll
        for (int i = 0; i < 4; i++)
#pragma unroll
            for (int j = 0; j < 4; j++)
                acc[i][j] = __builtin_amdgcn_mfma_f32_16x16x32_bf16(af[i], bfr[j], acc[i][j], 0, 0, 0);
    }

    u16* outs[3] = {oq, ov, og};
    u16* O = outs[nBlk >> 10];
    const int nIn = nBlk & 1023;
#pragma unroll
    for (int i = 0; i < 4; i++) {
        int row0 = mBlk + wm + i * 16 + quad * 4;
#pragma unroll
        for (int j = 0; j < 4; j++) {
            int col = nIn + wn + j * 16 + l16;
#pragma unroll
            for (int r = 0; r < 4; r++)
                O[(size_t)(row0 + r) * DM + col] = f2bf(acc[i][j][r]);
        }
    }
}

// output projection: C (f32) = A @ B^T, N=1024
__global__ __launch_bounds__(256)
void gemm_out(const u16* __restrict__ A, const u16* __restrict__ B,
              float* __restrict__ C, int N, int K) {
    __shared__ u16 As[128 * 32];
    __shared__ u16 Bs[128 * 32];

    const int tid  = threadIdx.x;
    const int wave = tid >> 6;
    const int lane = tid & 63;
    const int quad = lane >> 4;
    const int l16  = lane & 15;
    const int mBlk = blockIdx.x * 128;
    const int nBlk = blockIdx.y * 128;
    const int wm   = (wave >> 1) * 64;
    const int wn   = (wave & 1) * 64;

    const int srow   = wave * 16 + (lane >> 2);
    const int schunk = (lane & 3) * 8;

    const u16* gA0 = A + (size_t)(mBlk + srow) * K + schunk;
    const u16* gA1 = gA0 + (size_t)64 * K;
    const u16* gB0 = B + (size_t)(nBlk + srow) * K + schunk;
    const u16* gB1 = gB0 + (size_t)64 * K;

    u16* lA0 = As + wave * 16 * 32;
    u16* lA1 = lA0 + 64 * 32;
    u16* lB0 = Bs + wave * 16 * 32;
    u16* lB1 = lB0 + 64 * 32;

    f32x4 acc[4][4] = {};

    for (int kt = 0; kt < K; kt += 32) {
        __syncthreads();
        gld_lds16(gA0 + kt, lA0);
        gld_lds16(gA1 + kt, lA1);
        gld_lds16(gB0 + kt, lB0);
        gld_lds16(gB1 + kt, lB1);
        __syncthreads();

        mfma_in af[4], bfr[4];
#pragma unroll
        for (int i = 0; i < 4; i++)
            af[i] = *(const mfma_in*)&As[(wm + i * 16 + l16) * 32 + quad * 8];
#pragma unroll
        for (int j = 0; j < 4; j++)
            bfr[j] = *(const mfma_in*)&Bs[(wn + j * 16 + l16) * 32 + quad * 8];
#pragma unroll
        for (int i = 0; i < 4; i++)
#pragma unroll
            for (int j = 0; j < 4; j++)
                acc[i][j] = __builtin_amdgcn_mfma_f32_16x16x32_bf16(af[i], bfr[j], acc[i][j], 0, 0, 0);
    }

#pragma unroll
    for (int i = 0; i < 4; i++) {
        int row0 = mBlk + wm + i * 16 + quad * 4;
#pragma unroll
        for (int j = 0; j < 4; j++) {
            int col = nBlk + wn + j * 16 + l16;
#pragma unroll
            for (int r = 0; r < 4; r++)
                C[(size_t)(row0 + r) * N + col] = acc[i][j][r];
        }
    }
}

// ---------------------------------------------------------------- scan phase A
__global__ __launch_bounds__(256)
void scan_ends(const u16* __restrict__ v, const float* __restrict__ beta,
               float* __restrict__ ebuf) {
    int d = blockIdx.x * 256 + threadIdx.x;
    int c = blockIdx.y, b = blockIdx.z;
    int h = d >> 6;
    float lam = 1.0f / (1.0f + __expf(-beta[h]));
    size_t idx = ((size_t)b * LL + (size_t)c * LC2) * DM + d;
    float s = 0.0f;
#pragma unroll
    for (int i = 0; i < LC2; i++) {
        s = lam * s + bf2f(v[idx]);
        idx += DM;
    }
    ebuf[((size_t)b * CC2 + c) * DM + d] = s;
}

// ---------------------------------------------------------------- scan phase B
__global__ __launch_bounds__(256)
void scan_carry(const float* __restrict__ ebuf, const float* __restrict__ beta,
                float* __restrict__ carry) {
    int ch = blockIdx.x * 256 + threadIdx.x;  // 0..BB*DM-1
    int b = ch >> 10, d = ch & 1023;
    int h = d >> 6;
    float lam = 1.0f / (1.0f + __expf(-beta[h]));
    float lamC = lam;
    for (int i = 0; i < 4; i++) lamC *= lamC;  // lam^16
    float cur = 0.0f;
#pragma unroll 8
    for (int c = 0; c < CC2; c++) {
        size_t idx = ((size_t)b * CC2 + c) * DM + d;
        carry[idx] = cur;
        cur = lamC * cur + ebuf[idx];
    }
}

// ---------------------------------------------------------------- scan phase C:
// seeded re-scan + y=q*state + LayerNorm + SiLU gate -> bf16
__global__ __launch_bounds__(256)
void scan_ln_gate(const u16* __restrict__ v, const u16* __restrict__ q,
                  const u16* __restrict__ g, const float* __restrict__ carry,
                  const float* __restrict__ beta, const float* __restrict__ gamma,
                  const float* __restrict__ lnb, u16* __restrict__ out) {
    __shared__ float red[2][8];
    const int t = threadIdx.x;
    const int c = blockIdx.x, b = blockIdx.y;
    const int wave = t >> 6, lane = t & 63;
    const int d0 = t * 4;
    const int h = d0 >> 6;
    float lam = 1.0f / (1.0f + __expf(-beta[h]));
    float4 gm = ((const float4*)gamma)[t];
    float4 bt = ((const float4*)lnb)[t];
    float4 cr = *(const float4*)(carry + ((size_t)b * CC2 + c) * DM + d0);
    float s0 = cr.x, s1 = cr.y, s2 = cr.z, s3 = cr.w;
    size_t base = ((size_t)b * LL + (size_t)c * LC2) * DM + d0;

    for (int i = 0; i < LC2; i++) {
        ushort4 v4 = *(const ushort4*)(v + base);
        ushort4 q4 = *(const ushort4*)(q + base);
        ushort4 g4 = *(const ushort4*)(g + base);
        s0 = lam * s0 + bf2f(v4.x);
        s1 = lam * s1 + bf2f(v4.y);
        s2 = lam * s2 + bf2f(v4.z);
        s3 = lam * s3 + bf2f(v4.w);
        float y0 = bf2f(q4.x) * s0, y1 = bf2f(q4.y) * s1;
        float y2 = bf2f(q4.z) * s2, y3 = bf2f(q4.w) * s3;
        float sum = y0 + y1 + y2 + y3;
        float sq  = y0 * y0 + y1 * y1 + y2 * y2 + y3 * y3;
#pragma unroll
        for (int off = 32; off > 0; off >>= 1) {
            sum += __shfl_xor(sum, off);
            sq  += __shfl_xor(sq, off);
        }
        int p = i & 1;
        if (lane == 0) { red[p][wave] = sum; red[p][4 + wave] = sq; }
        __syncthreads();
        float ts = red[p][0] + red[p][1] + red[p][2] + red[p][3];
        float tq = red[p][4] + red[p][5] + red[p][6] + red[p][7];
        float mu  = ts * (1.0f / DM);
        float inv = rsqrtf(tq * (1.0f / DM) - mu * mu + 1e-5f);

        float gv0 = bf2f(g4.x), gv1 = bf2f(g4.y), gv2 = bf2f(g4.z), gv3 = bf2f(g4.w);
        float x0 = ((y0 - mu) * inv * gm.x + bt.x) * (gv0 / (1.0f + __expf(-gv0)));
        float x1 = ((y1 - mu) * inv * gm.y + bt.y) * (gv1 / (1.0f + __expf(-gv1)));
        float x2 = ((y2 - mu) * inv * gm.z + bt.z) * (gv2 / (1.0f + __expf(-gv2)));
        float x3 = ((y3 - mu) * inv * gm.w + bt.w) * (gv3 / (1.0f + __expf(-gv3)));
        ushort4 o;
        o.x = f2bf(x0); o.y = f2bf(x1); o.z = f2bf(x2); o.w = f2bf(x3);
        *(ushort4*)(out + base) = o;
        base += DM;
    }
}

// ---------------------------------------------------------------- launcher
extern "C" void kernel_launch(void* const* d_in, const int* in_sizes, int n_in,
                              void* d_out, int out_size, void* d_ws, size_t ws_size,
                              hipStream_t stream) {
    const float* x     = (const float*)d_in[0];
    const float* Wq    = (const float*)d_in[1];
    const float* Wv    = (const float*)d_in[2];
    const float* Wg    = (const float*)d_in[3];
    const float* Wo    = (const float*)d_in[4];
    const float* beta  = (const float*)d_in[5];
    const float* gamma = (const float*)d_in[6];
    const float* lnb   = (const float*)d_in[7];

    // workspace layout (bf16 elements) — xb..Wob contiguous for cvt_all
    u16* xb  = (u16*)d_ws;                    // reused as y_final
    u16* Wqb = xb + (size_t)MM * DM;          // Wq,Wv,Wg contiguous = 3072x1024 concat
    u16* Wob = Wqb + (size_t)3 * DM * DM;
    u16* qb  = Wob + (size_t)DM * DM;
    u16* vb  = qb + (size_t)MM * DM;
    u16* gb  = vb + (size_t)MM * DM;
    float* ebuf  = (float*)(gb + (size_t)MM * DM);   // BB*CC2*DM f32
    float* carry = ebuf + (size_t)BB * CC2 * DM;
    u16* yfin = xb;

    // 1) fp32 -> bf16, single launch
    cvt_all<<<(XF4 + 4 * WF4 + 255) / 256, 256, 0, stream>>>(x, Wq, Wv, Wg, Wo, xb);

    // 2) fused q/v/g projection (N=3072 concat) — 3072 blocks = 12/CU launched
    dim3 gq(MM / 128, 3 * DM / 128);
    gemm_qvg<<<gq, 256, 0, stream>>>(xb, Wqb, qb, vb, gb, DM);

    // 3) retention scan (chunked) + fused LN + SiLU gate
    dim3 gs(DM / 256, CC2, BB);
    scan_ends<<<gs, 256, 0, stream>>>(vb, beta, ebuf);
    scan_carry<<<(BB * DM) / 256, 256, 0, stream>>>(ebuf, beta, carry);
    dim3 gf(CC2, BB);
    scan_ln_gate<<<gf, 256, 0, stream>>>(vb, qb, gb, carry, beta, gamma, lnb, yfin);

    // 4) output projection (fp32 out)
    dim3 go(MM / 128, DM / 128);
    gemm_out<<<go, 256, 0, stream>>>(yfin, Wob, (float*)d_out, DM, DM);
}

// Round 4
// 346.930 us; speedup vs baseline: 1.1842x; 1.0902x over previous
//
#include <hip/hip_runtime.h>

// Problem constants (MultiScaleRetention: B=4, L=4096, D=1024, H=16, DH=64)
#define BB 4
#define LL 4096
#define DM 1024
#define NH 16
#define MM (BB * LL)   // 16384 rows
#define CC2 256        // scan chunks per sequence
#define LC2 16         // chunk length (CC2*LC2 == LL)

typedef unsigned short u16;
typedef float f32x4 __attribute__((ext_vector_type(4)));
typedef __bf16 mfma_in __attribute__((ext_vector_type(8)));

__device__ __forceinline__ u16 f2bf(float f) {
    unsigned u = __float_as_uint(f);
    u += 0x7FFFu + ((u >> 16) & 1u);   // RNE
    return (u16)(u >> 16);
}
__device__ __forceinline__ float bf2f(u16 u) {
    return __uint_as_float(((unsigned)u) << 16);
}

// async global->LDS, 16B per lane; LDS dest = wave-uniform base + lane*16
__device__ __forceinline__ void gld_lds16(const u16* g, u16* l) {
    __builtin_amdgcn_global_load_lds(
        (const __attribute__((address_space(1))) void*)g,
        (__attribute__((address_space(3))) void*)l,
        16, 0, 0);
}

// ---------------------------------------------------------------- conversions
#define XF4 (MM * DM / 4)
#define WF4 (DM * DM / 4)
__global__ __launch_bounds__(256)
void cvt_all(const float* __restrict__ x,
             const float* __restrict__ w0, const float* __restrict__ w1,
             const float* __restrict__ w2, const float* __restrict__ w3,
             u16* __restrict__ dst) {
    int i = blockIdx.x * 256 + threadIdx.x;
    const float* src;
    int si;
    if (i < XF4) { src = x; si = i; }
    else {
        int j = i - XF4;
        const float* ws[4] = {w0, w1, w2, w3};
        src = ws[j >> 18];
        si = j & (WF4 - 1);
    }
    float4 f = ((const float4*)src)[si];
    ushort4 o;
    o.x = f2bf(f.x); o.y = f2bf(f.y); o.z = f2bf(f.z); o.w = f2bf(f.w);
    ((ushort4*)dst)[i] = o;
}

// ---------------------------------------------------------------- GEMM main loop
// BK=64 (As/Bs 16KiB each), XOR bank swizzle: LDS row = 64 u16 (8 chunks of 16B),
// chunk at (row, logical c) stored at phys = c ^ (row&7).
// Staging: lane l of wave w, instr j covers row j*32+w*8+(l>>3), phys chunk l&7
//   -> logical chunk (l&7)^(l>>3); per-row 128B stays one contiguous (permuted) segment.
// Fragment read: row wm+i*16+l16, k-step s, logical chunk 4s+quad
//   -> phys (4s+quad)^(l16&7): 16 lanes of a quad spread over 8 chunks = 2-way (free).
__device__ __forceinline__ void mainloop_bk64(
    const u16* __restrict__ A, const u16* __restrict__ B, int K,
    int mBlk, int nBlk, u16* As, u16* Bs, f32x4 acc[4][4]) {
    const int tid  = threadIdx.x;
    const int wave = tid >> 6;
    const int lane = tid & 63;
    const int quad = lane >> 4;
    const int l16  = lane & 15;
    const int wm   = (wave >> 1) * 64;
    const int wn   = (wave & 1) * 64;

    const int srow8 = wave * 8 + (lane >> 3);
    const int cOff  = ((lane & 7) ^ (lane >> 3)) * 8;

    const u16* gA[4];
    const u16* gB[4];
    u16* lA[4];
    u16* lB[4];
#pragma unroll
    for (int j = 0; j < 4; j++) {
        gA[j] = A + (size_t)(mBlk + j * 32 + srow8) * K + cOff;
        gB[j] = B + (size_t)(nBlk + j * 32 + srow8) * K + cOff;
        lA[j] = As + (j * 32 + wave * 8) * 64;
        lB[j] = Bs + (j * 32 + wave * 8) * 64;
    }

    int rowA[4], rowB[4];
#pragma unroll
    for (int i = 0; i < 4; i++) {
        rowA[i] = (wm + i * 16 + l16) * 64;
        rowB[i] = (wn + i * 16 + l16) * 64;
    }
    const int c0 = ((quad    ) ^ (l16 & 7)) * 8;
    const int c1 = ((quad + 4) ^ (l16 & 7)) * 8;

    for (int kt = 0; kt < K; kt += 64) {
        __syncthreads();   // protect previous iteration's LDS reads
#pragma unroll
        for (int j = 0; j < 4; j++) gld_lds16(gA[j] + kt, lA[j]);
#pragma unroll
        for (int j = 0; j < 4; j++) gld_lds16(gB[j] + kt, lB[j]);
        __syncthreads();   // drains vmcnt -> staged data visible

#pragma unroll
        for (int s = 0; s < 2; s++) {
            const int cs = s ? c1 : c0;
            mfma_in af[4], bfr[4];
#pragma unroll
            for (int i = 0; i < 4; i++)
                af[i] = *(const mfma_in*)&As[rowA[i] + cs];
#pragma unroll
            for (int j = 0; j < 4; j++)
                bfr[j] = *(const mfma_in*)&Bs[rowB[j] + cs];
#pragma unroll
            for (int i = 0; i < 4; i++)
#pragma unroll
                for (int j = 0; j < 4; j++)
                    acc[i][j] = __builtin_amdgcn_mfma_f32_16x16x32_bf16(af[i], bfr[j], acc[i][j], 0, 0, 0);
        }
    }
}

// fused q/v/g projection: B = concatenated 3072x1024 weights; 3 bf16 outputs
__global__ __launch_bounds__(256)
void gemm_qvg(const u16* __restrict__ A, const u16* __restrict__ B,
              u16* __restrict__ oq, u16* __restrict__ ov, u16* __restrict__ og,
              int K) {
    __shared__ u16 As[128 * 64];
    __shared__ u16 Bs[128 * 64];
    const int mBlk = blockIdx.x * 128;
    const int nBlk = blockIdx.y * 128;

    f32x4 acc[4][4] = {};
    mainloop_bk64(A, B, K, mBlk, nBlk, As, Bs, acc);

    const int tid  = threadIdx.x;
    const int wave = tid >> 6;
    const int lane = tid & 63;
    const int quad = lane >> 4;
    const int l16  = lane & 15;
    const int wm   = (wave >> 1) * 64;
    const int wn   = (wave & 1) * 64;

    u16* outs[3] = {oq, ov, og};
    u16* O = outs[nBlk >> 10];
    const int nIn = nBlk & 1023;
#pragma unroll
    for (int i = 0; i < 4; i++) {
        int row0 = mBlk + wm + i * 16 + quad * 4;
#pragma unroll
        for (int j = 0; j < 4; j++) {
            int col = nIn + wn + j * 16 + l16;
#pragma unroll
            for (int r = 0; r < 4; r++)
                O[(size_t)(row0 + r) * DM + col] = f2bf(acc[i][j][r]);
        }
    }
}

// output projection: C (f32) = A @ B^T
__global__ __launch_bounds__(256)
void gemm_out(const u16* __restrict__ A, const u16* __restrict__ B,
              float* __restrict__ C, int N, int K) {
    __shared__ u16 As[128 * 64];
    __shared__ u16 Bs[128 * 64];
    const int mBlk = blockIdx.x * 128;
    const int nBlk = blockIdx.y * 128;

    f32x4 acc[4][4] = {};
    mainloop_bk64(A, B, K, mBlk, nBlk, As, Bs, acc);

    const int tid  = threadIdx.x;
    const int wave = tid >> 6;
    const int lane = tid & 63;
    const int quad = lane >> 4;
    const int l16  = lane & 15;
    const int wm   = (wave >> 1) * 64;
    const int wn   = (wave & 1) * 64;

#pragma unroll
    for (int i = 0; i < 4; i++) {
        int row0 = mBlk + wm + i * 16 + quad * 4;
#pragma unroll
        for (int j = 0; j < 4; j++) {
            int col = nBlk + wn + j * 16 + l16;
#pragma unroll
            for (int r = 0; r < 4; r++)
                C[(size_t)(row0 + r) * N + col] = acc[i][j][r];
        }
    }
}

// ---------------------------------------------------------------- scan phase A
__global__ __launch_bounds__(256)
void scan_ends(const u16* __restrict__ v, const float* __restrict__ beta,
               float* __restrict__ ebuf) {
    int d = blockIdx.x * 256 + threadIdx.x;
    int c = blockIdx.y, b = blockIdx.z;
    int h = d >> 6;
    float lam = 1.0f / (1.0f + __expf(-beta[h]));
    size_t idx = ((size_t)b * LL + (size_t)c * LC2) * DM + d;
    float s = 0.0f;
#pragma unroll
    for (int i = 0; i < LC2; i++) {
        s = lam * s + bf2f(v[idx]);
        idx += DM;
    }
    ebuf[((size_t)b * CC2 + c) * DM + d] = s;
}

// ---------------------------------------------------------------- scan phase B
__global__ __launch_bounds__(256)
void scan_carry(const float* __restrict__ ebuf, const float* __restrict__ beta,
                float* __restrict__ carry) {
    int ch = blockIdx.x * 256 + threadIdx.x;  // 0..BB*DM-1
    int b = ch >> 10, d = ch & 1023;
    int h = d >> 6;
    float lam = 1.0f / (1.0f + __expf(-beta[h]));
    float lamC = lam;
    for (int i = 0; i < 4; i++) lamC *= lamC;  // lam^16
    float cur = 0.0f;
#pragma unroll 8
    for (int c = 0; c < CC2; c++) {
        size_t idx = ((size_t)b * CC2 + c) * DM + d;
        carry[idx] = cur;
        cur = lamC * cur + ebuf[idx];
    }
}

// ---------------------------------------------------------------- scan phase C:
// seeded re-scan + y=q*state + LayerNorm + SiLU gate -> bf16
__global__ __launch_bounds__(256)
void scan_ln_gate(const u16* __restrict__ v, const u16* __restrict__ q,
                  const u16* __restrict__ g, const float* __restrict__ carry,
                  const float* __restrict__ beta, const float* __restrict__ gamma,
                  const float* __restrict__ lnb, u16* __restrict__ out) {
    __shared__ float red[2][8];
    const int t = threadIdx.x;
    const int c = blockIdx.x, b = blockIdx.y;
    const int wave = t >> 6, lane = t & 63;
    const int d0 = t * 4;
    const int h = d0 >> 6;
    float lam = 1.0f / (1.0f + __expf(-beta[h]));
    float4 gm = ((const float4*)gamma)[t];
    float4 bt = ((const float4*)lnb)[t];
    float4 cr = *(const float4*)(carry + ((size_t)b * CC2 + c) * DM + d0);
    float s0 = cr.x, s1 = cr.y, s2 = cr.z, s3 = cr.w;
    size_t base = ((size_t)b * LL + (size_t)c * LC2) * DM + d0;

    for (int i = 0; i < LC2; i++) {
        ushort4 v4 = *(const ushort4*)(v + base);
        ushort4 q4 = *(const ushort4*)(q + base);
        ushort4 g4 = *(const ushort4*)(g + base);
        s0 = lam * s0 + bf2f(v4.x);
        s1 = lam * s1 + bf2f(v4.y);
        s2 = lam * s2 + bf2f(v4.z);
        s3 = lam * s3 + bf2f(v4.w);
        float y0 = bf2f(q4.x) * s0, y1 = bf2f(q4.y) * s1;
        float y2 = bf2f(q4.z) * s2, y3 = bf2f(q4.w) * s3;
        float sum = y0 + y1 + y2 + y3;
        float sq  = y0 * y0 + y1 * y1 + y2 * y2 + y3 * y3;
#pragma unroll
        for (int off = 32; off > 0; off >>= 1) {
            sum += __shfl_xor(sum, off);
            sq  += __shfl_xor(sq, off);
        }
        int p = i & 1;
        if (lane == 0) { red[p][wave] = sum; red[p][4 + wave] = sq; }
        __syncthreads();
        float ts = red[p][0] + red[p][1] + red[p][2] + red[p][3];
        float tq = red[p][4] + red[p][5] + red[p][6] + red[p][7];
        float mu  = ts * (1.0f / DM);
        float inv = rsqrtf(tq * (1.0f / DM) - mu * mu + 1e-5f);

        float gv0 = bf2f(g4.x), gv1 = bf2f(g4.y), gv2 = bf2f(g4.z), gv3 = bf2f(g4.w);
        float x0 = ((y0 - mu) * inv * gm.x + bt.x) * (gv0 / (1.0f + __expf(-gv0)));
        float x1 = ((y1 - mu) * inv * gm.y + bt.y) * (gv1 / (1.0f + __expf(-gv1)));
        float x2 = ((y2 - mu) * inv * gm.z + bt.z) * (gv2 / (1.0f + __expf(-gv2)));
        float x3 = ((y3 - mu) * inv * gm.w + bt.w) * (gv3 / (1.0f + __expf(-gv3)));
        ushort4 o;
        o.x = f2bf(x0); o.y = f2bf(x1); o.z = f2bf(x2); o.w = f2bf(x3);
        *(ushort4*)(out + base) = o;
        base += DM;
    }
}

// ---------------------------------------------------------------- launcher
extern "C" void kernel_launch(void* const* d_in, const int* in_sizes, int n_in,
                              void* d_out, int out_size, void* d_ws, size_t ws_size,
                              hipStream_t stream) {
    const float* x     = (const float*)d_in[0];
    const float* Wq    = (const float*)d_in[1];
    const float* Wv    = (const float*)d_in[2];
    const float* Wg    = (const float*)d_in[3];
    const float* Wo    = (const float*)d_in[4];
    const float* beta  = (const float*)d_in[5];
    const float* gamma = (const float*)d_in[6];
    const float* lnb   = (const float*)d_in[7];

    // workspace layout (bf16 elements) — xb..Wob contiguous for cvt_all
    u16* xb  = (u16*)d_ws;                    // reused as y_final
    u16* Wqb = xb + (size_t)MM * DM;          // Wq,Wv,Wg concat = 3072x1024
    u16* Wob = Wqb + (size_t)3 * DM * DM;
    u16* qb  = Wob + (size_t)DM * DM;
    u16* vb  = qb + (size_t)MM * DM;
    u16* gb  = vb + (size_t)MM * DM;
    float* ebuf  = (float*)(gb + (size_t)MM * DM);   // BB*CC2*DM f32
    float* carry = ebuf + (size_t)BB * CC2 * DM;
    u16* yfin = xb;

    // 1) fp32 -> bf16, single launch
    cvt_all<<<(XF4 + 4 * WF4 + 255) / 256, 256, 0, stream>>>(x, Wq, Wv, Wg, Wo, xb);

    // 2) fused q/v/g projection (N=3072 concat)
    dim3 gq(MM / 128, 3 * DM / 128);
    gemm_qvg<<<gq, 256, 0, stream>>>(xb, Wqb, qb, vb, gb, DM);

    // 3) retention scan (chunked) + fused LN + SiLU gate
    dim3 gs(DM / 256, CC2, BB);
    scan_ends<<<gs, 256, 0, stream>>>(vb, beta, ebuf);
    scan_carry<<<(BB * DM) / 256, 256, 0, stream>>>(ebuf, beta, carry);
    dim3 gf(CC2, BB);
    scan_ln_gate<<<gf, 256, 0, stream>>>(vb, qb, gb, carry, beta, gamma, lnb, yfin);

    // 4) output projection (fp32 out)
    dim3 go(MM / 128, DM / 128);
    gemm_out<<<go, 256, 0, stream>>>(yfin, Wob, (float*)d_out, DM, DM);
}